// Round 2
// baseline (1987.134 us; speedup 1.0000x reference)
//
#include <hip/hip_runtime.h>

// samx_qkv_1bit R13: packed-record + speculative-rla + rec[p] reuse.
// R12 overlapped query/key chains; still latency-bound (~2220 cyc/step,
// VALUBusy 16%, 1 wave/SIMD). R13 shortens the per-hop DS cost and kills
// the walk3-entry hop:
//   - state packed into one u64 rec[s] = tr0|tr1|fl|ml (16b fields) + u16
//     rla[]. Every pointer-chase hop = ONE ds_read_b64 (was 2 loads to 2
//     arrays); early-key d-read (was 3 loads) and tail gather (was 2) too.
//     Same 40960 B LDS -> 4 blocks/CU, all 1024 rows co-resident.
//   - walk2 speculatively co-loads rla[fv] with flml[fv] (and rla[p] with
//     the entry rec[p]) -> walk3's entry check needs no new load: -1 hop
//     per step, always on the critical path.
//   - walk2's entry load rec[p] IS next step's query prefetch (w==p).
//     Patched in registers for this step's deferred stores; the patch is
//     provably complete: rec[p] can only change via prefix tk[cid]=j
//     (cid==p), redirect tk[cid]=bb (cid==p), clone fl[d]=bb (d==p) --
//     two ballots + one compare on the uniform p. Tail = one rec[nv]
//     gather (after all stores; in-order DS makes it coherent).
// Cold paths (chain > 64) keep the R10-verified serial fallback, ported
// field-for-field to the packed record.

#define NSTATES 4096
#define TLEN 2048

typedef unsigned long long u64m;

__device__ __forceinline__ int f_tr(u64m r, int s) {   // transition by symbol
  return (int)(short)(unsigned short)(r >> (s << 4));
}
__device__ __forceinline__ int f_fl(u64m r) {          // suffix link
  return (int)(short)(unsigned short)(r >> 32);
}
__device__ __forceinline__ int f_ml(u64m r) {          // max length
  return (int)(r >> 48);
}

__global__ __launch_bounds__(64)
void samx_main(const float* __restrict__ q,
               const float* __restrict__ k,
               unsigned* __restrict__ outpos,
               int T, int C) {
  __shared__ u64m           reca[NSTATES];  // tr0[15:0] tr1[31:16] fl[47:32] ml[63:48]
  __shared__ unsigned short rla[NSTATES];   // last end pos, 0xFFFF = -1

  unsigned short* recw = (unsigned short*)reca;  // [4*s + f]: f=0 tr0,1 tr1,2 fl,3 ml
  unsigned*       rech = (unsigned*)reca;        // [2*s+1] = fl|ml<<16 (old flml word)

  const int row = blockIdx.x;
  const int b = row / C;
  const int c = row - b * C;
  const int lane = threadIdx.x;

  for (int s = lane; s < NSTATES; s += 64) {
    reca[s] = 0x0000FFFFFFFFFFFFull;  // tr0=tr1=fl=-1, ml=0
    rla[s] = 0xFFFFu;
  }

  const size_t rowbase = (size_t)b * (size_t)T * (size_t)C + (size_t)c;
  const float* qr = q + rowbase;
  const float* kr = k + rowbase;
  unsigned* outr = outpos + rowbase;

  // Pre-binarize: lane L holds bits t = 32L..32L+31 of q and k.
  unsigned qw = 0u, kw = 0u;
  {
    const int t0 = lane * 32;
#pragma unroll 8
    for (int jj = 0; jj < 32; ++jj) {
      const int t = t0 + jj;
      if (qr[(size_t)t * C] > 0.0f) qw |= (1u << jj);
      if (kr[(size_t)t * C] > 0.0f) kw |= (1u << jj);
    }
  }
  __syncthreads();

  int cid = 0;                  // my chain slot's state id (slot = lane)
  bool cval = (lane == 0);      // slot validity (valid slots contiguous)
  bool trunc = false;

  int g = 0;    // last state (uniform; used by fallback)
  int mlg = 0;  // ml[g]
  int u = 1;    // next free state id
  int w = 0;    // query-match state
  int h = 0;    // query-match length

  // ---- prologue prefetch for i = 0 ----
  int qs = (int)(__builtin_amdgcn_readlane((int)qw, 0) & 1);
  int ks = (int)(__builtin_amdgcn_readlane((int)kw, 0) & 1);
  u64m pf_rec = reca[0];   // rec[cid] (all cids are 0)
  u64m recp   = pf_rec;    // rec[w]   (w = 0)

  for (int i = 0; i < T; ++i) {
    const bool hot = !trunc;
    const u64m rk  = pf_rec;          // rec[cid], pre-key value (prefetched)
    const int img  = f_tr(rk, ks);
    const int myml = f_ml(rk);

    const int j = u++;
    const int mlj = mlg + 1;

    // persists early -> deferred
    int d = -1, bb = -1, flj = 0, ndd = 0, newlen = 2, pushed = 0;
    bool prefl = false, inrun = false;

    if (hot) {
      // ---------- EARLY KEY: everything not visible to the query ----------
      const u64m brkmask = __ballot(cval && img != -1);
      const bool nobrk = (brkmask == 0);
      const int t2 = nobrk ? 64 : (int)__builtin_ctzll(brkmask);
      const int t2c = (t2 > 63) ? 63 : t2;
      d = __builtin_amdgcn_readlane(img, t2c);   // uniform idx -> no DS hop
      const int mlp = __builtin_amdgcn_readlane(myml, t2c);
      const int dld = (d < 0) ? 0 : d;
      prefl = cval && (lane < t2);

      // ONE b64: tr0,tr1,fl,ml of d (tr patched below if d is a prefix node)
      const u64m recd = reca[dld];
      int lm1 = lane - 1; if (lm1 < 0) lm1 = 0;
      const int previmg = __builtin_amdgcn_ds_bpermute(lm1 << 2, img);

      const unsigned fmdhi = (unsigned)(recd >> 32);  // fl|ml of d
      if (!nobrk) {
        const int mld = (int)(fmdhi >> 16);
        if (mlp + 1 == mld) {
          flj = d;
        } else {
          bb = u++;  // clone of d with length mlp+1
          int dtr0 = f_tr(recd, 0);
          int dtr1 = f_tr(recd, 1);
          // register patch of the deferred prefix stores' effect on tk[d]
          const u64m pb = __ballot(prefl && cid == d);
          if (pb != 0ull) { if (ks) dtr1 = j; else dtr0 = j; }
          if (lane == 0) {
            // bb unreachable until deferred link stores land -> safe early
            // rl[bb] copy elided: bb is slot 1 of the new chain -> stamped i
            reca[bb] = (u64m)(unsigned short)dtr0
                     | ((u64m)(unsigned short)dtr1 << 16)
                     | ((u64m)(fmdhi & 0xFFFFu) << 32)
                     | ((u64m)(unsigned)(mlp + 1) << 48);
          }
          flj = bb;
        }
      }
      if (lane == 0)  // j likewise unreachable during the query
        rech[2 * j + 1] = (unsigned)(flj & 0xFFFF) | ((unsigned)mlj << 16);

      // redirect run (clone only): contiguous img==d from t2
      if (bb >= 0) {
        const u64m eq = __ballot(cval && img == d) >> t2;
        const int runlen = (eq == ~0ull) ? 64 : (int)__builtin_ctzll(~eq);
        inrun = cval && lane >= t2 && lane < t2 + runlen;
      }
      // run-start mask from PRE-redirect img (identical post-redirect)
      const bool rs = cval && lane >= t2 && (lane == t2 || img != previmg);
      const u64m rsmask = __ballot(rs);
      ndd = (int)__builtin_popcountll(rsmask);
      newlen = ndd + 2;  // [j] + ndd images + [root]
      const unsigned below =
          __builtin_amdgcn_mbcnt_hi((unsigned)(rsmask >> 32),
              __builtin_amdgcn_mbcnt_lo((unsigned)rsmask, 0u));
      // run-start #q pushes its image to slot q+1; others push to trash
      // slot 0 (only lane 0 reads it, and lane 0 overrides with j).
      const int dst = rs ? ((int)below + 1) : 0;
      pushed = __builtin_amdgcn_ds_permute(dst << 2, img);
    }

    // ============ QUERY (wave-uniform; sees pre-key automaton) ============
    int p = w, x = h;
    {
      u64m rr = recp;  // prefetched rec[w] (patched for last step's stores)
      for (;;) {
        if (p == -1) { p = 0; x = 0; break; }
        const int tv = f_tr(rr, qs);
        if (tv != -1) { p = tv; x = x + 1; break; }
        const int mp = f_ml(rr);
        if (x > mp) x = mp;
        p = f_fl(rr);
        if (p == -1) { p = 0; x = 0; break; }
        rr = reca[p];   // ONE b64 per hop
      }
    }

    // walk2 entry: rec[p] (also next step's query prefetch) + speculative rla
    const u64m recP = reca[p];
    int rlv = (int)(short)rla[p];
    unsigned fmv = (unsigned)(recP >> 32);
    int vst = p;
    for (;;) {
      const int fv = (int)(short)(fmv & 0xFFFFu);
      if (fv == -1) break;
      const unsigned fmf = rech[2 * fv + 1];
      const int rlf = (int)(short)rla[fv];   // speculative, same hop
      if ((int)(fmf >> 16) < x) break;
      vst = fv; fmv = fmf; rlv = rlf;
    }
    int rv = -1;
    for (;;) {
      if (vst == -1) { rv = -1; break; }
      if ((int)(fmv >> 16) > 0 && rlv >= 0) { rv = rlv; break; }  // entry free
      vst = (int)(short)(fmv & 0xFFFFu);
      if (vst == -1) { rv = -1; break; }
      fmv = rech[2 * vst + 1];
      rlv = (int)(short)rla[vst];
    }
    w = p; h = x;

    if (hot) {
      // -------- DEFERRED KEY: stores the query must not observe --------
      if (prefl) recw[4 * cid + ks] = (unsigned short)j;
      if (inrun) recw[4 * cid + ks] = (unsigned short)bb;
      if (bb >= 0 && lane == 0) recw[4 * d + 2] = (unsigned short)bb;  // fl[d]=bb
      if (lane == 0) outr[(size_t)i * C] = (unsigned)(rv + 1);

      // next-iter query prefetch: patch recP with this step's stores.
      // rec[p] mutations are exactly {prefix j, redirect bb} at cid==p and
      // clone fl[d]=bb at d==p (p != j,bb: p predates this step).
      u64m rp = recP;
      if (bb >= 0 && p == d)
        rp = (rp & ~(0xFFFFull << 32)) | ((u64m)(unsigned short)bb << 32);
      const int sh = ks << 4;
      if (__ballot(prefl && cid == p) != 0ull)
        rp = (rp & ~(0xFFFFull << sh)) | ((u64m)(unsigned short)j << sh);
      if (__ballot(inrun && cid == p) != 0ull)
        rp = (rp & ~(0xFFFFull << sh)) | ((u64m)(unsigned short)bb << sh);
      recp = rp;

      // new chain: [j, flj, run-start images #1.., root]
      int nv = 0;  // default root/padding (safe gather next step)
      if (lane == 0) nv = j;
      else if (lane == 1) nv = flj;
      else if (lane - 1 < ndd) nv = pushed;
      const bool nval = (lane < newlen);
      if (nval) rla[nv] = (unsigned short)i;   // after query's rla reads

      const bool overflow = (newlen > 64);
      if (overflow) {  // cold: stamp the unstored tail serially
        const int nv63 = __builtin_amdgcn_readlane(nv, 63);
        if (lane == 0) {
          int vp = (int)(short)(rech[2 * nv63 + 1] & 0xFFFFu);
          while (vp != -1) {
            rla[vp] = (unsigned short)i;
            vp = (int)(short)(rech[2 * vp + 1] & 0xFFFFu);
          }
        }
      }
      cid = nv; cval = nval; trunc = overflow;
    } else {
      // ======= COLD fallback: reference-exact serial step (R10-verified) ====
      int pcur = g, d2 = -1, idbrk = -1;
      for (;;) {
        if (pcur == -1) break;
        const u64m rr = reca[pcur];
        const int tv = f_tr(rr, ks);
        if (tv != -1) { d2 = tv; idbrk = pcur; break; }
        if (lane == 0) recw[4 * pcur + ks] = (unsigned short)j;
        pcur = f_fl(rr);
      }
      int fl2 = 0;
      if (d2 != -1) {
        const int mlp2 = f_ml(reca[idbrk]);
        const u64m rd2 = reca[d2];
        const int mld = f_ml(rd2);
        if (mlp2 + 1 == mld) {
          fl2 = d2;
        } else {
          const int bbc = u++;
          const int drl = (int)(short)rla[d2];
          if (lane == 0) {
            reca[bbc] = (u64m)(unsigned short)f_tr(rd2, 0)
                      | ((u64m)(unsigned short)f_tr(rd2, 1) << 16)
                      | ((u64m)((unsigned)(rd2 >> 32) & 0xFFFFu) << 32)
                      | ((u64m)(unsigned)(mlp2 + 1) << 48);
            rla[bbc] = (unsigned short)drl;
            recw[4 * d2 + 2] = (unsigned short)bbc;   // fl[d2] = bbc
          }
          fl2 = bbc;
          int p3 = idbrk;
          for (;;) {
            if (p3 == -1) break;
            const u64m r3 = reca[p3];
            const int tv3 = f_tr(r3, ks);
            if (tv3 != d2) break;
            if (lane == 0) recw[4 * p3 + ks] = (unsigned short)bbc;
            p3 = f_fl(r3);
          }
        }
      }
      if (lane == 0) {
        rech[2 * j + 1] = (unsigned)(fl2 & 0xFFFF) | ((unsigned)mlj << 16);
        outr[(size_t)i * C] = (unsigned)(rv + 1);
      }
      // full propagation walk; rebuild lane chain while stamping
      int vp = j, ncs = 0;
      bool tr2 = false;
      for (;;) {
        if (vp == -1) break;
        if (ncs < 64) { if (lane == ncs) cid = vp; ++ncs; }
        else tr2 = true;
        if (lane == 0) rla[vp] = (unsigned short)i;
        vp = (int)(short)(rech[2 * vp + 1] & 0xFFFFu);
      }
      cval = (lane < ncs);
      trunc = tr2;
      recp = reca[w];   // fresh (post-stores) query prefetch
    }
    g = j; mlg = mlj;

    // ---- tail prefetch for i+1: ONE per-lane gather (in-order DS => sees
    // every store of this step; next step's early stores touch only fresh
    // j'/bb' != cid) ----
    if (i + 1 < T) {
      pf_rec = reca[cid];
      const int in = i + 1;
      const unsigned qwn = (unsigned)__builtin_amdgcn_readlane((int)qw, in >> 5);
      const unsigned kwn = (unsigned)__builtin_amdgcn_readlane((int)kw, in >> 5);
      qs = (int)((qwn >> (in & 31)) & 1u);
      ks = (int)((kwn >> (in & 31)) & 1u);
    }
  }
}

// Fully parallel epilogue: vidx (u32, = r+1, 0 = no match) -> sign*e.
__global__ __launch_bounds__(256)
void samx_epilogue(const float* __restrict__ v,
                   const float* __restrict__ e,
                   unsigned* __restrict__ out,
                   int T, int C, int total) {
  const int idx = blockIdx.x * 256 + threadIdx.x;
  if (idx >= total) return;
  const unsigned vidx = out[idx];
  const int c = idx % C;
  const int bi = idx / C;
  const int b = bi / T;
  const float ev = e[c];
  float val = -ev;  // y=0
  if (vidx != 0u) {
    if (v[((size_t)b * (size_t)T + (size_t)vidx) * (size_t)C + (size_t)c] > 0.0f)
      val = ev;
  }
  out[idx] = __float_as_uint(val);
}

extern "C" void kernel_launch(void* const* d_in, const int* in_sizes, int n_in,
                              void* d_out, int out_size, void* d_ws, size_t ws_size,
                              hipStream_t stream) {
  const float* q = (const float*)d_in[0];
  const float* k = (const float*)d_in[1];
  const float* v = (const float*)d_in[2];
  const float* e = (const float*)d_in[3];

  const int C = in_sizes[3];
  const int T = TLEN;
  const int B = in_sizes[0] / (T * C);
  const int total = out_size;

  samx_main<<<dim3(B * C), dim3(64), 0, stream>>>(q, k, (unsigned*)d_out, T, C);
  samx_epilogue<<<dim3((total + 255) / 256), dim3(256), 0, stream>>>(
      v, e, (unsigned*)d_out, T, C, total);
}